// Round 11
// baseline (242.921 us; speedup 1.0000x reference)
//
#include <hip/hip_runtime.h>
#include <hip/hip_bf16.h>

#define D 128
#define NBUCKET 64
#define BCAP 16384   // per-bucket edge capacity (mean 10k -> huge margin)

typedef __bf16 bf16x8 __attribute__((ext_vector_type(8)));
typedef float f32x4 __attribute__((ext_vector_type(4)));

// stored col j  <->  true col PI(j) = (j&7)*16 + (j>>3);  PI_inv(c) = (c&15)*8 + (c>>4)

// ---------------- prep: pack weights + zero bucket cursors ----------------
__global__ void prep_kernel(const float* __restrict__ W1, const float* __restrict__ W2,
                            __bf16* __restrict__ pw, int* __restrict__ bucket_cursor) {
    int b = blockIdx.x;
    if (b < 128) {
        int t = b * 256 + threadIdx.x;  // 0..32767
        int which = t >> 14, idx = t & 16383;
        const float* W = which ? W2 : W1;
        float w = W[idx];
        int k = idx >> 7, nn = idx & 127;
        int ks = which ? (((k & 15) << 3) | (k >> 4)) : k;  // PI_inv for layer 2
        int ntile = nn >> 4, nl = nn & 15;
        int kchunk = ks >> 5, quad = (ks >> 3) & 3, j = ks & 7;
        int o = (((ntile * 4 + kchunk) * 64 + quad * 16 + nl) << 3) + j;
        pw[(size_t)which * 16384 + o] = (__bf16)w;
    } else {
        if (threadIdx.x < NBUCKET) bucket_cursor[threadIdx.x] = 0;
    }
}

// ------- mega1: gemm1 (blocks [0,gb)) + edge bucketize (blocks [gb, gb+eab)) -------
// gemm1: Zs = X(fp32) @ W1bf16, A split 2-term; B-frags straight from global
// (32 KB PW is L1/L2-resident; no LDS stage, no barrier -> waves uncoupled).
__global__ void mega1_kernel(const float* __restrict__ X, const __bf16* __restrict__ PW,
                             __bf16* __restrict__ Zs, int nrows, int gb,
                             const int* __restrict__ src, const int* __restrict__ dst,
                             int* __restrict__ bucket_cursor, int2* __restrict__ bucket_edges,
                             int e, int bucketW) {
    __shared__ int hist[NBUCKET];
    __shared__ int gbase[NBUCKET];
    int t = threadIdx.x;
    int b = blockIdx.x;
    if (b >= gb) {
        // ---- bucketize path ----
        if (t < NBUCKET) hist[t] = 0;
        __syncthreads();
        int i0 = ((b - gb) * 256 + t) * 4;
        int sv[4], dv[4], bk[4], ls[4];
        int nv = 0;
        if (i0 + 4 <= e) {
            int4 s4 = *(const int4*)(src + i0);
            int4 d4 = *(const int4*)(dst + i0);
            sv[0] = s4.x; sv[1] = s4.y; sv[2] = s4.z; sv[3] = s4.w;
            dv[0] = d4.x; dv[1] = d4.y; dv[2] = d4.z; dv[3] = d4.w;
            nv = 4;
        } else {
            for (int i = i0; i < e; i++) { sv[nv] = src[i]; dv[nv] = dst[i]; nv++; }
        }
        for (int u = 0; u < nv; u++) {
            bk[u] = dv[u] / bucketW;
            ls[u] = atomicAdd(&hist[bk[u]], 1);
        }
        __syncthreads();
        if (t < NBUCKET) gbase[t] = atomicAdd(&bucket_cursor[t], hist[t]);
        __syncthreads();
        for (int u = 0; u < nv; u++) {
            int pos = bk[u] * BCAP + gbase[bk[u]] + ls[u];
            bucket_edges[pos] = make_int2(sv[u], dv[u]);
        }
        return;
    }
    // ---- gemm1 path ----
    int wave = t >> 6, lane = t & 63;
    int qm = lane & 15, quad = lane >> 4;
    int r0 = b * 64 + wave * 16;
    int row = r0 + qm;
    bool valid = row < nrows;
    const float* xr = X + (size_t)row * D + quad * 8;

    bf16x8 ahi[4], alo[4];
#pragma unroll
    for (int c = 0; c < 4; c++) {
        float4 zf = {0.f, 0.f, 0.f, 0.f};
        float4 xa = valid ? ((const float4*)(xr + c * 32))[0] : zf;
        float4 xb = valid ? ((const float4*)(xr + c * 32))[1] : zf;
        float xs[8] = {xa.x, xa.y, xa.z, xa.w, xb.x, xb.y, xb.z, xb.w};
        bf16x8 h, l;
#pragma unroll
        for (int j = 0; j < 8; j++) {
            float v = xs[j];
            __bf16 hh = (__bf16)v;
            h[j] = hh;
            l[j] = (__bf16)(v - (float)hh);
        }
        ahi[c] = h; alo[c] = l;
    }

    f32x4 acc[8];
#pragma unroll
    for (int nt = 0; nt < 8; nt++) acc[nt] = (f32x4){0.f, 0.f, 0.f, 0.f};

    const bf16x8* PW8 = (const bf16x8*)PW;
#pragma unroll
    for (int c = 0; c < 4; c++) {
#pragma unroll
        for (int nt = 0; nt < 8; nt++) {
            bf16x8 bb = PW8[(nt * 4 + c) * 64 + lane];
            acc[nt] = __builtin_amdgcn_mfma_f32_16x16x32_bf16(ahi[c], bb, acc[nt], 0, 0, 0);
            acc[nt] = __builtin_amdgcn_mfma_f32_16x16x32_bf16(alo[c], bb, acc[nt], 0, 0, 0);
        }
    }

    // C/D: true col = nt*16+qm -> stored col qm*8+nt; row = quad*4+reg
#pragma unroll
    for (int reg = 0; reg < 4; reg++) {
        int orow = r0 + quad * 4 + reg;
        if (orow < nrows) {
            bf16x8 o;
#pragma unroll
            for (int nt = 0; nt < 8; nt++) o[nt] = (__bf16)acc[nt][reg];
            *(bf16x8*)(Zs + (size_t)orow * D + qm * 8) = o;
        }
    }
}

// ------- count2: LDS-binned degree count for a node subrange; writes counts, dinv, -------
// ------- and the block's edge-sum into partial[b] (256 blocks).                     -------
__global__ void count2_kernel(const int2* __restrict__ bucket_edges,
                              const int* __restrict__ bucket_cursor,
                              int* __restrict__ counts, float* __restrict__ dinv,
                              int* __restrict__ partial, int n, int bucketW, int subW) {
    __shared__ int bins[400];
    __shared__ int sm[256];
    int b = blockIdx.x, t = threadIdx.x;
    int bk = b >> 2, j = b & 3;
    int ns = bk * bucketW + j * subW;
    int be = min((bk + 1) * bucketW, n);
    int ne = min(ns + subW, be);
    int w = ne - ns;
    if (w <= 0) { if (t == 0) partial[b] = 0; return; }
    for (int i = t; i < w; i += 256) bins[i] = 0;
    __syncthreads();
    int m = bucket_cursor[bk];
    const int2* eb = bucket_edges + (size_t)bk * BCAP;
    for (int i = t; i < m; i += 256) {
        int d = eb[i].y;
        if (d >= ns && d < ne) atomicAdd(&bins[d - ns], 1);
    }
    __syncthreads();
    int s = 0;
    for (int i = t; i < w; i += 256) {
        int c = bins[i];
        counts[ns + i] = c;
        dinv[ns + i] = rsqrtf((float)(c + 1));  // +1 self loop
        s += c;
    }
    sm[t] = s; __syncthreads();
    for (int off = 128; off > 0; off >>= 1) { if (t < off) sm[t] += sm[t + off]; __syncthreads(); }
    if (t == 0) partial[b] = sm[0];
}

// ------- scan_fill: top-scan of partial done per-block in LDS (no scan_top launch), -------
// ------- then local row_ptr from counts, then CSR scatter with LDS cursors.         -------
__global__ void scanfill_kernel(const int2* __restrict__ bucket_edges,
                                const int* __restrict__ bucket_cursor,
                                const int* __restrict__ counts,
                                const int* __restrict__ partial,
                                int* __restrict__ row_ptr, int* __restrict__ csr,
                                int n, int bucketW, int subW) {
    __shared__ int cur[400];
    __shared__ int sm[256];
    __shared__ int ptmp[256];
    int b = blockIdx.x, t = threadIdx.x;
    // top-scan: inclusive scan of the 256 block sums, recomputed locally
    int pv = partial[t];
    ptmp[t] = pv; __syncthreads();
    for (int off = 1; off < 256; off <<= 1) {
        int u = (t >= off) ? ptmp[t - off] : 0;
        __syncthreads();
        ptmp[t] += u;
        __syncthreads();
    }
    int bk = b >> 2, j = b & 3;
    int ns = bk * bucketW + j * subW;
    int be = min((bk + 1) * bucketW, n);
    int ne = min(ns + subW, be);
    int w = ne - ns;
    if (w <= 0) return;
    int blockbase = ptmp[b] - partial[b];  // exclusive prefix for this block
    int i0 = t * 2;
    int c0 = (i0 < w) ? counts[ns + i0] : 0;
    int c1 = (i0 + 1 < w) ? counts[ns + i0 + 1] : 0;
    sm[t] = c0 + c1; __syncthreads();
    int own = c0 + c1;
    for (int off = 1; off < 256; off <<= 1) {
        int u = (t >= off) ? sm[t - off] : 0;
        __syncthreads();
        sm[t] += u;
        __syncthreads();
    }
    int base = blockbase + sm[t] - own;
    if (i0 < w)     { row_ptr[ns + i0] = base;          cur[i0] = base; }
    if (i0 + 1 < w) { row_ptr[ns + i0 + 1] = base + c0; cur[i0 + 1] = base + c0; }
    __syncthreads();
    int m = bucket_cursor[bk];
    const int2* eb = bucket_edges + (size_t)bk * BCAP;
    for (int i = t; i < m; i += 256) {
        int2 ed = eb[i];
        if (ed.y >= ns && ed.y < ne) {
            int pos = atomicAdd(&cur[ed.y - ns], 1);
            csr[pos] = ed.x;
        }
    }
}

// ------- agg1 + gemm2 fused per 64-node tile: h-tile lives only in LDS -------
__global__ void agg1gemm2_kernel(const __bf16* __restrict__ Zs, const int* __restrict__ row_ptr,
                                 const int* __restrict__ counts, const int* __restrict__ csr,
                                 const float* __restrict__ dinv, const float* __restrict__ bias,
                                 const __bf16* __restrict__ PW2, __bf16* __restrict__ Z2, int n) {
    __shared__ bf16x8 htile[64][17];  // stride 17 -> 2-way bank aliasing (free)
    int t = threadIdx.x;
    int r0 = blockIdx.x * 64;
    const bf16x8* Z8 = (const bf16x8*)Zs;
    int c = t & 15;
    int nsub = t >> 4;  // 0..15
#pragma unroll
    for (int rd = 0; rd < 4; rd++) {
        int v = r0 + rd * 16 + nsub;
        bf16x8 o = {};
        if (v < n) {
            float dv = dinv[v];
            bf16x8 zc = Z8[(size_t)v * 16 + c];
            float sw = dv * dv;
            float acc[8];
#pragma unroll
            for (int jj = 0; jj < 8; jj++) acc[jj] = (float)zc[jj] * sw;
            int start = row_ptr[v], cnt = counts[v];
            int i = 0;
            for (; i + 4 <= cnt; i += 4) {
                int s0 = csr[start + i], s1 = csr[start + i + 1];
                int s2 = csr[start + i + 2], s3 = csr[start + i + 3];
                bf16x8 m0 = Z8[(size_t)s0 * 16 + c];
                bf16x8 m1 = Z8[(size_t)s1 * 16 + c];
                bf16x8 m2 = Z8[(size_t)s2 * 16 + c];
                bf16x8 m3 = Z8[(size_t)s3 * 16 + c];
                float w0 = dinv[s0] * dv, w1 = dinv[s1] * dv;
                float w2 = dinv[s2] * dv, w3 = dinv[s3] * dv;
#pragma unroll
                for (int jj = 0; jj < 8; jj++) acc[jj] = fmaf(w0, (float)m0[jj], acc[jj]);
#pragma unroll
                for (int jj = 0; jj < 8; jj++) acc[jj] = fmaf(w1, (float)m1[jj], acc[jj]);
#pragma unroll
                for (int jj = 0; jj < 8; jj++) acc[jj] = fmaf(w2, (float)m2[jj], acc[jj]);
#pragma unroll
                for (int jj = 0; jj < 8; jj++) acc[jj] = fmaf(w3, (float)m3[jj], acc[jj]);
            }
            for (; i < cnt; i++) {
                int s0 = csr[start + i];
                float w0 = dinv[s0] * dv;
                bf16x8 m0 = Z8[(size_t)s0 * 16 + c];
#pragma unroll
                for (int jj = 0; jj < 8; jj++) acc[jj] = fmaf(w0, (float)m0[jj], acc[jj]);
            }
#pragma unroll
            for (int jj = 0; jj < 8; jj++) o[jj] = (__bf16)fmaxf(acc[jj] + bias[jj * 16 + c], 0.f);
        }
        htile[rd * 16 + nsub][c] = o;
    }
    __syncthreads();

    // ---- gemm2 phase (B-frags from global; L1/L2-resident 32 KB) ----
    int wave = t >> 6, lane = t & 63;
    int qm = lane & 15, quad = lane >> 4;
    int rowl = wave * 16 + qm;
    bf16x8 a[4];
#pragma unroll
    for (int c4 = 0; c4 < 4; c4++) a[c4] = htile[rowl][c4 * 4 + quad];

    f32x4 acc2[8];
#pragma unroll
    for (int nt = 0; nt < 8; nt++) acc2[nt] = (f32x4){0.f, 0.f, 0.f, 0.f};

    const bf16x8* B8 = (const bf16x8*)PW2;
#pragma unroll
    for (int c4 = 0; c4 < 4; c4++) {
#pragma unroll
        for (int nt = 0; nt < 8; nt++) {
            bf16x8 bb = B8[(nt * 4 + c4) * 64 + lane];
            acc2[nt] = __builtin_amdgcn_mfma_f32_16x16x32_bf16(a[c4], bb, acc2[nt], 0, 0, 0);
        }
    }

#pragma unroll
    for (int reg = 0; reg < 4; reg++) {
        int orow = r0 + wave * 16 + quad * 4 + reg;
        if (orow < n) {
            bf16x8 o;
#pragma unroll
            for (int nt = 0; nt < 8; nt++) o[nt] = (__bf16)acc2[nt][reg];
            *(bf16x8*)(Z2 + (size_t)orow * D + qm * 8) = o;
        }
    }
}

// ------- agg2 + fc fused: out[v,2] = relu(agg(Z2) + b2) @ Wfc + bfc -------
__global__ void agg2_fc_kernel(const __bf16* __restrict__ Zs, const int* __restrict__ row_ptr,
                               const int* __restrict__ counts, const int* __restrict__ csr,
                               const float* __restrict__ dinv, const float* __restrict__ bias,
                               const float* __restrict__ Wfc, const float* __restrict__ bfc,
                               float* __restrict__ out, int n) {
    int t = blockIdx.x * 256 + threadIdx.x;
    int v = t >> 4, c = t & 15;
    if (v >= n) return;
    float dv = dinv[v];
    const bf16x8* Z8 = (const bf16x8*)Zs;
    bf16x8 zc = Z8[(size_t)v * 16 + c];
    float sw = dv * dv;
    float acc[8];
#pragma unroll
    for (int j = 0; j < 8; j++) acc[j] = (float)zc[j] * sw;
    int start = row_ptr[v], cnt = counts[v];
    int i = 0;
    for (; i + 4 <= cnt; i += 4) {
        int s0 = csr[start + i], s1 = csr[start + i + 1];
        int s2 = csr[start + i + 2], s3 = csr[start + i + 3];
        bf16x8 m0 = Z8[(size_t)s0 * 16 + c];
        bf16x8 m1 = Z8[(size_t)s1 * 16 + c];
        bf16x8 m2 = Z8[(size_t)s2 * 16 + c];
        bf16x8 m3 = Z8[(size_t)s3 * 16 + c];
        float w0 = dinv[s0] * dv, w1 = dinv[s1] * dv;
        float w2 = dinv[s2] * dv, w3 = dinv[s3] * dv;
#pragma unroll
        for (int j = 0; j < 8; j++) acc[j] = fmaf(w0, (float)m0[j], acc[j]);
#pragma unroll
        for (int j = 0; j < 8; j++) acc[j] = fmaf(w1, (float)m1[j], acc[j]);
#pragma unroll
        for (int j = 0; j < 8; j++) acc[j] = fmaf(w2, (float)m2[j], acc[j]);
#pragma unroll
        for (int j = 0; j < 8; j++) acc[j] = fmaf(w3, (float)m3[j], acc[j]);
    }
    for (; i < cnt; i++) {
        int s0 = csr[start + i];
        float w0 = dinv[s0] * dv;
        bf16x8 m0 = Z8[(size_t)s0 * 16 + c];
#pragma unroll
        for (int j = 0; j < 8; j++) acc[j] = fmaf(w0, (float)m0[j], acc[j]);
    }
    float a0 = 0.f, a1 = 0.f;
#pragma unroll
    for (int j = 0; j < 8; j++) {
        int p = j * 16 + c;  // true col
        float hj = fmaxf(acc[j] + bias[p], 0.f);
        a0 = fmaf(hj, Wfc[p * 2], a0);
        a1 = fmaf(hj, Wfc[p * 2 + 1], a1);
    }
#pragma unroll
    for (int off = 8; off > 0; off >>= 1) {
        a0 += __shfl_down(a0, off, 16);
        a1 += __shfl_down(a1, off, 16);
    }
    if (c == 0) {
        out[(size_t)v * 2 + 0] = a0 + bfc[0];
        out[(size_t)v * 2 + 1] = a1 + bfc[1];
    }
}

// ---------------- launch ----------------

extern "C" void kernel_launch(void* const* d_in, const int* in_sizes, int n_in,
                              void* d_out, int out_size, void* d_ws, size_t ws_size,
                              hipStream_t stream) {
    const float* x   = (const float*)d_in[0];
    const int*   ei  = (const int*)d_in[1];
    const float* W1  = (const float*)d_in[2];
    const float* b1  = (const float*)d_in[3];
    const float* W2  = (const float*)d_in[4];
    const float* b2  = (const float*)d_in[5];
    const float* Wfc = (const float*)d_in[6];
    const float* bfc = (const float*)d_in[7];
    float* out = (float*)d_out;

    int n = in_sizes[0] / D;   // 100000
    int e = in_sizes[1] / 2;   // 640000
    const int* src = ei;
    const int* dst = ei + e;

    int bucketW = (n + NBUCKET - 1) / NBUCKET;   // 1563
    int subW = (bucketW + 3) / 4;                // 391 (fits bins[400])

    // workspace layout (16B-aligned at these sizes)
    char* ws = (char*)d_ws;
    size_t nb = (size_t)n * 4;
    int*    counts  = (int*)(ws);
    float*  dinv    = (float*)(ws + nb);
    int*    rowptr  = (int*)(ws + 2 * nb);
    int*    partial = (int*)(ws + 3 * nb);                    // 1024 B
    int*    bcur    = (int*)(ws + 3 * nb + 1024);             // 1024 B
    int2*   bedges  = (int2*)(ws + 3 * nb + 2048);            // 64*BCAP*8 = 8 MB
    size_t  off1    = 3 * nb + 2048 + (size_t)NBUCKET * BCAP * 8;
    int*    csr     = (int*)(ws + off1);                      // e*4
    __bf16* pw      = (__bf16*)(ws + off1 + (size_t)e * 4);   // 64 KB packed (W1|W2)
    __bf16* z1      = (__bf16*)(ws + off1 + (size_t)e * 4 + 65536);
    __bf16* z2      = z1 + (size_t)n * D;

    int eab = ((e + 3) / 4 + 255) / 256;       // bucketize blocks (625)
    int gb  = (n + 63) / 64;                   // tile blocks (1563)
    int ab  = ((n * 16) + 255) / 256;          // agg blocks (6250)

    prep_kernel<<<129, 256, 0, stream>>>(W1, W2, pw, bcur);
    // gemm1 + bucketize co-scheduled (independent; MFMA hides scatter latency)
    mega1_kernel<<<gb + eab, 256, 0, stream>>>(x, pw, z1, n, gb, src, dst,
                                               bcur, bedges, e, bucketW);
    count2_kernel<<<256, 256, 0, stream>>>(bedges, bcur, counts, dinv, partial, n, bucketW, subW);
    scanfill_kernel<<<256, 256, 0, stream>>>(bedges, bcur, counts, partial, rowptr, csr,
                                             n, bucketW, subW);
    // layer 1 agg + layer 2 gemm fused (h-tile in LDS only)
    agg1gemm2_kernel<<<gb, 256, 0, stream>>>(z1, rowptr, counts, csr, dinv, b1,
                                             pw + 16384, z2, n);
    agg2_fc_kernel<<<ab, 256, 0, stream>>>(z2, rowptr, counts, csr, dinv, b2, Wfc, bfc, out, n);
}

// Round 12
// 237.773 us; speedup vs baseline: 1.0217x; 1.0217x over previous
//
#include <hip/hip_runtime.h>
#include <hip/hip_bf16.h>

#define D 128
#define NBUCKET 64
#define BCAP 16384   // per-bucket edge capacity (mean 10k -> huge margin)

typedef __bf16 bf16x8 __attribute__((ext_vector_type(8)));
typedef float f32x4 __attribute__((ext_vector_type(4)));

// stored col j  <->  true col PI(j) = (j&7)*16 + (j>>3);  PI_inv(c) = (c&15)*8 + (c>>4)

// ---------------- prep: pack weights + zero bucket cursors + zero degree hist ----------------
__global__ void prep_kernel(const float* __restrict__ W1, const float* __restrict__ W2,
                            __bf16* __restrict__ pw, int* __restrict__ bucket_cursor,
                            int* __restrict__ deghist) {
    int b = blockIdx.x;
    if (b < 128) {
        int t = b * 256 + threadIdx.x;  // 0..32767
        int which = t >> 14, idx = t & 16383;
        const float* W = which ? W2 : W1;
        float w = W[idx];
        int k = idx >> 7, nn = idx & 127;
        int ks = which ? (((k & 15) << 3) | (k >> 4)) : k;  // PI_inv for layer 2
        int ntile = nn >> 4, nl = nn & 15;
        int kchunk = ks >> 5, quad = (ks >> 3) & 3, j = ks & 7;
        int o = (((ntile * 4 + kchunk) * 64 + quad * 16 + nl) << 3) + j;
        pw[(size_t)which * 16384 + o] = (__bf16)w;
    } else {
        int t = threadIdx.x;
        if (t < NBUCKET) bucket_cursor[t] = 0;
        else if (t < 128) deghist[t - 64] = 0;
    }
}

// ------- mega1: gemm1 (blocks [0,gb)) + edge bucketize (blocks [gb, gb+eab)) -------
// gemm1: Zs = X(fp32) @ W1bf16, A split 2-term, B staged in LDS (proven R10 form).
__global__ void mega1_kernel(const float* __restrict__ X, const __bf16* __restrict__ PW,
                             __bf16* __restrict__ Zs, int nrows, int gb,
                             const int* __restrict__ src, const int* __restrict__ dst,
                             int* __restrict__ bucket_cursor, int2* __restrict__ bucket_edges,
                             int e, int bucketW) {
    __shared__ __align__(16) char smem[32768];
    int t = threadIdx.x;
    int b = blockIdx.x;
    if (b >= gb) {
        // ---- bucketize path ----
        int* hist = (int*)smem;          // 64
        int* gbase = hist + 64;          // 64
        if (t < NBUCKET) hist[t] = 0;
        __syncthreads();
        int i0 = ((b - gb) * 256 + t) * 4;
        int sv[4], dv[4], bk[4], ls[4];
        int nv = 0;
        if (i0 + 4 <= e) {
            int4 s4 = *(const int4*)(src + i0);
            int4 d4 = *(const int4*)(dst + i0);
            sv[0] = s4.x; sv[1] = s4.y; sv[2] = s4.z; sv[3] = s4.w;
            dv[0] = d4.x; dv[1] = d4.y; dv[2] = d4.z; dv[3] = d4.w;
            nv = 4;
        } else {
            for (int i = i0; i < e; i++) { sv[nv] = src[i]; dv[nv] = dst[i]; nv++; }
        }
        for (int u = 0; u < nv; u++) {
            bk[u] = dv[u] / bucketW;
            ls[u] = atomicAdd(&hist[bk[u]], 1);
        }
        __syncthreads();
        if (t < NBUCKET) gbase[t] = atomicAdd(&bucket_cursor[t], hist[t]);
        __syncthreads();
        for (int u = 0; u < nv; u++) {
            int pos = bk[u] * BCAP + gbase[bk[u]] + ls[u];
            bucket_edges[pos] = make_int2(sv[u], dv[u]);
        }
        return;
    }
    // ---- gemm1 path ----
    bf16x8* sB = (bf16x8*)smem;  // 32 KB packed W
    const bf16x8* PW8 = (const bf16x8*)PW;
#pragma unroll
    for (int i = 0; i < 8; i++) sB[t + 256 * i] = PW8[t + 256 * i];

    int wave = t >> 6, lane = t & 63;
    int qm = lane & 15, quad = lane >> 4;
    int r0 = b * 64 + wave * 16;
    int row = r0 + qm;
    bool valid = row < nrows;
    const float* xr = X + (size_t)row * D + quad * 8;

    bf16x8 ahi[4], alo[4];
#pragma unroll
    for (int c = 0; c < 4; c++) {
        float4 zf = {0.f, 0.f, 0.f, 0.f};
        float4 xa = valid ? ((const float4*)(xr + c * 32))[0] : zf;
        float4 xb = valid ? ((const float4*)(xr + c * 32))[1] : zf;
        float xs[8] = {xa.x, xa.y, xa.z, xa.w, xb.x, xb.y, xb.z, xb.w};
        bf16x8 h, l;
#pragma unroll
        for (int j = 0; j < 8; j++) {
            float v = xs[j];
            __bf16 hh = (__bf16)v;
            h[j] = hh;
            l[j] = (__bf16)(v - (float)hh);
        }
        ahi[c] = h; alo[c] = l;
    }

    f32x4 acc[8];
#pragma unroll
    for (int nt = 0; nt < 8; nt++) acc[nt] = (f32x4){0.f, 0.f, 0.f, 0.f};

    __syncthreads();

#pragma unroll
    for (int c = 0; c < 4; c++) {
#pragma unroll
        for (int nt = 0; nt < 8; nt++) {
            bf16x8 bb = sB[(nt * 4 + c) * 64 + lane];
            acc[nt] = __builtin_amdgcn_mfma_f32_16x16x32_bf16(ahi[c], bb, acc[nt], 0, 0, 0);
            acc[nt] = __builtin_amdgcn_mfma_f32_16x16x32_bf16(alo[c], bb, acc[nt], 0, 0, 0);
        }
    }

    // C/D: true col = nt*16+qm -> stored col qm*8+nt; row = quad*4+reg
#pragma unroll
    for (int reg = 0; reg < 4; reg++) {
        int orow = r0 + quad * 4 + reg;
        if (orow < nrows) {
            bf16x8 o;
#pragma unroll
            for (int nt = 0; nt < 8; nt++) o[nt] = (__bf16)acc[nt][reg];
            *(bf16x8*)(Zs + (size_t)orow * D + qm * 8) = o;
        }
    }
}

// ------- count2: LDS-binned degree count; writes counts, dinv, block edge-sum, -------
// ------- and accumulates the global degree histogram (64 bins, block-privatized). -------
__global__ void count2_kernel(const int2* __restrict__ bucket_edges,
                              const int* __restrict__ bucket_cursor,
                              int* __restrict__ counts, float* __restrict__ dinv,
                              int* __restrict__ partial, int* __restrict__ deghist,
                              int n, int bucketW, int subW) {
    __shared__ int bins[400];
    __shared__ int sm[256];
    __shared__ int hb[64];
    int b = blockIdx.x, t = threadIdx.x;
    int bk = b >> 2, j = b & 3;
    int ns = bk * bucketW + j * subW;
    int be = min((bk + 1) * bucketW, n);
    int ne = min(ns + subW, be);
    int w = ne - ns;
    if (w <= 0) { if (t == 0) partial[b] = 0; return; }
    for (int i = t; i < w; i += 256) bins[i] = 0;
    if (t < 64) hb[t] = 0;
    __syncthreads();
    int m = bucket_cursor[bk];
    const int2* eb = bucket_edges + (size_t)bk * BCAP;
    for (int i = t; i < m; i += 256) {
        int d = eb[i].y;
        if (d >= ns && d < ne) atomicAdd(&bins[d - ns], 1);
    }
    __syncthreads();
    int s = 0;
    for (int i = t; i < w; i += 256) {
        int c = bins[i];
        counts[ns + i] = c;
        dinv[ns + i] = rsqrtf((float)(c + 1));  // +1 self loop
        atomicAdd(&hb[min(c, 63)], 1);
        s += c;
    }
    sm[t] = s; __syncthreads();
    for (int off = 128; off > 0; off >>= 1) { if (t < off) sm[t] += sm[t + off]; __syncthreads(); }
    if (t == 0) partial[b] = sm[0];
    if (t < 64 && hb[t]) atomicAdd(&deghist[t], hb[t]);
}

// ------- scan_top: exclusive scan of 256 block sums + 64-bin degree offsets -------
__global__ void scan_top(int* partial, int* deghist, int* degcur, int nb) {
    __shared__ int sm[256];
    int t = threadIdx.x;
    int v = (t < nb) ? partial[t] : 0;
    sm[t] = v; __syncthreads();
    for (int off = 1; off < 256; off <<= 1) {
        int u = (t >= off) ? sm[t - off] : 0;
        __syncthreads();
        sm[t] += u;
        __syncthreads();
    }
    if (t < nb) partial[t] = sm[t] - v;  // exclusive
    __syncthreads();
    int d = (t < 64) ? deghist[t] : 0;
    sm[t] = d; __syncthreads();
    for (int off = 1; off < 64; off <<= 1) {
        int u = (t >= off && t < 64) ? sm[t - off] : 0;
        __syncthreads();
        if (t < 64) sm[t] += u;
        __syncthreads();
    }
    if (t < 64) degcur[t] = sm[t] - d;  // running cursor, starts at exclusive offset
}

// ------- scan_fill: local row_ptr + CSR scatter + degree-sorted order scatter -------
__global__ void scanfill_kernel(const int2* __restrict__ bucket_edges,
                                const int* __restrict__ bucket_cursor,
                                const int* __restrict__ counts,
                                const int* __restrict__ partial,
                                int* __restrict__ row_ptr, int* __restrict__ csr,
                                int* __restrict__ degcur, int* __restrict__ order,
                                int n, int bucketW, int subW) {
    __shared__ int cur[400];
    __shared__ int sm[256];
    __shared__ int hb2[64];
    __shared__ int gb2[64];
    int b = blockIdx.x, t = threadIdx.x;
    int bk = b >> 2, j = b & 3;
    int ns = bk * bucketW + j * subW;
    int be = min((bk + 1) * bucketW, n);
    int ne = min(ns + subW, be);
    int w = ne - ns;
    if (w <= 0) return;
    if (t < 64) hb2[t] = 0;
    int i0 = t * 2;
    int c0 = (i0 < w) ? counts[ns + i0] : 0;
    int c1 = (i0 + 1 < w) ? counts[ns + i0 + 1] : 0;
    sm[t] = c0 + c1; __syncthreads();
    int own = c0 + c1;
    for (int off = 1; off < 256; off <<= 1) {
        int u = (t >= off) ? sm[t - off] : 0;
        __syncthreads();
        sm[t] += u;
        __syncthreads();
    }
    int base = partial[b] + sm[t] - own;
    if (i0 < w)     { row_ptr[ns + i0] = base;          cur[i0] = base; }
    if (i0 + 1 < w) { row_ptr[ns + i0 + 1] = base + c0; cur[i0 + 1] = base + c0; }
    // degree-order: local ranks within block per bin
    int bin0 = min(c0, 63), bin1 = min(c1, 63);
    int r0 = (i0 < w) ? atomicAdd(&hb2[bin0], 1) : 0;
    int r1 = (i0 + 1 < w) ? atomicAdd(&hb2[bin1], 1) : 0;
    __syncthreads();
    if (t < 64 && hb2[t]) gb2[t] = atomicAdd(&degcur[t], hb2[t]);
    __syncthreads();
    if (i0 < w)     order[gb2[bin0] + r0] = ns + i0;
    if (i0 + 1 < w) order[gb2[bin1] + r1] = ns + i0 + 1;
    __syncthreads();
    int m = bucket_cursor[bk];
    const int2* eb = bucket_edges + (size_t)bk * BCAP;
    for (int i = t; i < m; i += 256) {
        int2 ed = eb[i];
        if (ed.y >= ns && ed.y < ne) {
            int pos = atomicAdd(&cur[ed.y - ns], 1);
            csr[pos] = ed.x;
        }
    }
}

// ------- agg1 (degree-ordered): Hs[v] = relu(dinv^2*Zs[v] + sum w*Zs[s] + b1) -------
// 16 lanes/node, node = order[idx] -> waves process equal-degree nodes (no divergence).
__global__ void agg1_kernel(const __bf16* __restrict__ Zs, const int* __restrict__ row_ptr,
                            const int* __restrict__ counts, const int* __restrict__ csr,
                            const float* __restrict__ dinv, const float* __restrict__ bias,
                            const int* __restrict__ order, __bf16* __restrict__ Hs, int n) {
    int t = blockIdx.x * 256 + threadIdx.x;
    int idx = t >> 4, c = t & 15;
    if (idx >= n) return;
    int v = order[idx];
    float dv = dinv[v];
    const bf16x8* Z8 = (const bf16x8*)Zs;
    bf16x8 zc = Z8[(size_t)v * 16 + c];
    float sw = dv * dv;
    float acc[8];
#pragma unroll
    for (int j = 0; j < 8; j++) acc[j] = (float)zc[j] * sw;
    int start = row_ptr[v], cnt = counts[v];
    int i = 0;
    for (; i + 4 <= cnt; i += 4) {
        int s0 = csr[start + i], s1 = csr[start + i + 1];
        int s2 = csr[start + i + 2], s3 = csr[start + i + 3];
        bf16x8 m0 = Z8[(size_t)s0 * 16 + c];
        bf16x8 m1 = Z8[(size_t)s1 * 16 + c];
        bf16x8 m2 = Z8[(size_t)s2 * 16 + c];
        bf16x8 m3 = Z8[(size_t)s3 * 16 + c];
        float w0 = dinv[s0] * dv, w1 = dinv[s1] * dv;
        float w2 = dinv[s2] * dv, w3 = dinv[s3] * dv;
#pragma unroll
        for (int j = 0; j < 8; j++) acc[j] = fmaf(w0, (float)m0[j], acc[j]);
#pragma unroll
        for (int j = 0; j < 8; j++) acc[j] = fmaf(w1, (float)m1[j], acc[j]);
#pragma unroll
        for (int j = 0; j < 8; j++) acc[j] = fmaf(w2, (float)m2[j], acc[j]);
#pragma unroll
        for (int j = 0; j < 8; j++) acc[j] = fmaf(w3, (float)m3[j], acc[j]);
    }
    for (; i < cnt; i++) {
        int s0 = csr[start + i];
        float w0 = dinv[s0] * dv;
        bf16x8 m0 = Z8[(size_t)s0 * 16 + c];
#pragma unroll
        for (int j = 0; j < 8; j++) acc[j] = fmaf(w0, (float)m0[j], acc[j]);
    }
    bf16x8 o;
#pragma unroll
    for (int j = 0; j < 8; j++) o[j] = (__bf16)fmaxf(acc[j] + bias[j * 16 + c], 0.f);
    ((bf16x8*)Hs)[(size_t)v * 16 + c] = o;
}

// ---------------- GEMM2: Zs2 = Hs(bf16, PI cols) @ W2bf16, 1-term, B in LDS ----------------
__global__ void gemm2_mfma(const __bf16* __restrict__ Hs, const __bf16* __restrict__ PW,
                           __bf16* __restrict__ Zs, int nrows) {
    __shared__ bf16x8 sB[2048];  // 32 KB
    int t = threadIdx.x;
    const bf16x8* PW8 = (const bf16x8*)PW;
#pragma unroll
    for (int i = 0; i < 8; i++) sB[t + 256 * i] = PW8[t + 256 * i];

    int wave = t >> 6, lane = t & 63;
    int qm = lane & 15, quad = lane >> 4;
    int r0 = blockIdx.x * 64 + wave * 16;
    int row = r0 + qm;
    bool valid = row < nrows;
    const __bf16* hr = Hs + (size_t)row * D + quad * 8;

    bf16x8 a[4];
#pragma unroll
    for (int c = 0; c < 4; c++) {
        bf16x8 z8 = {};
        a[c] = valid ? *(const bf16x8*)(hr + c * 32) : z8;
    }

    f32x4 acc[8];
#pragma unroll
    for (int nt = 0; nt < 8; nt++) acc[nt] = (f32x4){0.f, 0.f, 0.f, 0.f};

    __syncthreads();

#pragma unroll
    for (int c = 0; c < 4; c++) {
#pragma unroll
        for (int nt = 0; nt < 8; nt++) {
            bf16x8 b = sB[(nt * 4 + c) * 64 + lane];
            acc[nt] = __builtin_amdgcn_mfma_f32_16x16x32_bf16(a[c], b, acc[nt], 0, 0, 0);
        }
    }

#pragma unroll
    for (int reg = 0; reg < 4; reg++) {
        int orow = r0 + quad * 4 + reg;
        if (orow < nrows) {
            bf16x8 o;
#pragma unroll
            for (int nt = 0; nt < 8; nt++) o[nt] = (__bf16)acc[nt][reg];
            *(bf16x8*)(Zs + (size_t)orow * D + qm * 8) = o;
        }
    }
}

// ------- agg2 + fc fused (degree-ordered): out[v,2] = relu(agg(Z2) + b2) @ Wfc + bfc -------
__global__ void agg2_fc_kernel(const __bf16* __restrict__ Zs, const int* __restrict__ row_ptr,
                               const int* __restrict__ counts, const int* __restrict__ csr,
                               const float* __restrict__ dinv, const float* __restrict__ bias,
                               const float* __restrict__ Wfc, const float* __restrict__ bfc,
                               const int* __restrict__ order, float* __restrict__ out, int n) {
    int t = blockIdx.x * 256 + threadIdx.x;
    int idx = t >> 4, c = t & 15;
    if (idx >= n) return;
    int v = order[idx];
    float dv = dinv[v];
    const bf16x8* Z8 = (const bf16x8*)Zs;
    bf16x8 zc = Z8[(size_t)v * 16 + c];
    float sw = dv * dv;
    float acc[8];
#pragma unroll
    for (int j = 0; j < 8; j++) acc[j] = (float)zc[j] * sw;
    int start = row_ptr[v], cnt = counts[v];
    int i = 0;
    for (; i + 4 <= cnt; i += 4) {
        int s0 = csr[start + i], s1 = csr[start + i + 1];
        int s2 = csr[start + i + 2], s3 = csr[start + i + 3];
        bf16x8 m0 = Z8[(size_t)s0 * 16 + c];
        bf16x8 m1 = Z8[(size_t)s1 * 16 + c];
        bf16x8 m2 = Z8[(size_t)s2 * 16 + c];
        bf16x8 m3 = Z8[(size_t)s3 * 16 + c];
        float w0 = dinv[s0] * dv, w1 = dinv[s1] * dv;
        float w2 = dinv[s2] * dv, w3 = dinv[s3] * dv;
#pragma unroll
        for (int j = 0; j < 8; j++) acc[j] = fmaf(w0, (float)m0[j], acc[j]);
#pragma unroll
        for (int j = 0; j < 8; j++) acc[j] = fmaf(w1, (float)m1[j], acc[j]);
#pragma unroll
        for (int j = 0; j < 8; j++) acc[j] = fmaf(w2, (float)m2[j], acc[j]);
#pragma unroll
        for (int j = 0; j < 8; j++) acc[j] = fmaf(w3, (float)m3[j], acc[j]);
    }
    for (; i < cnt; i++) {
        int s0 = csr[start + i];
        float w0 = dinv[s0] * dv;
        bf16x8 m0 = Z8[(size_t)s0 * 16 + c];
#pragma unroll
        for (int j = 0; j < 8; j++) acc[j] = fmaf(w0, (float)m0[j], acc[j]);
    }
    float a0 = 0.f, a1 = 0.f;
#pragma unroll
    for (int j = 0; j < 8; j++) {
        int p = j * 16 + c;  // true col
        float hj = fmaxf(acc[j] + bias[p], 0.f);
        a0 = fmaf(hj, Wfc[p * 2], a0);
        a1 = fmaf(hj, Wfc[p * 2 + 1], a1);
    }
#pragma unroll
    for (int off = 8; off > 0; off >>= 1) {
        a0 += __shfl_down(a0, off, 16);
        a1 += __shfl_down(a1, off, 16);
    }
    if (c == 0) {
        out[(size_t)v * 2 + 0] = a0 + bfc[0];
        out[(size_t)v * 2 + 1] = a1 + bfc[1];
    }
}

// ---------------- launch ----------------

extern "C" void kernel_launch(void* const* d_in, const int* in_sizes, int n_in,
                              void* d_out, int out_size, void* d_ws, size_t ws_size,
                              hipStream_t stream) {
    const float* x   = (const float*)d_in[0];
    const int*   ei  = (const int*)d_in[1];
    const float* W1  = (const float*)d_in[2];
    const float* b1  = (const float*)d_in[3];
    const float* W2  = (const float*)d_in[4];
    const float* b2  = (const float*)d_in[5];
    const float* Wfc = (const float*)d_in[6];
    const float* bfc = (const float*)d_in[7];
    float* out = (float*)d_out;

    int n = in_sizes[0] / D;   // 100000
    int e = in_sizes[1] / 2;   // 640000
    const int* src = ei;
    const int* dst = ei + e;

    int bucketW = (n + NBUCKET - 1) / NBUCKET;   // 1563
    int subW = (bucketW + 3) / 4;                // 391 (fits bins[400])

    // workspace layout (16B-aligned at these sizes)
    char* ws = (char*)d_ws;
    size_t nb = (size_t)n * 4;
    int*    counts  = (int*)(ws);
    float*  dinv    = (float*)(ws + nb);
    int*    rowptr  = (int*)(ws + 2 * nb);
    int*    partial = (int*)(ws + 3 * nb);                    // 1024 B
    int*    bcur    = (int*)(ws + 3 * nb + 1024);             // 256 B
    int*    deghist = (int*)(ws + 3 * nb + 1280);             // 256 B
    int*    degcur  = (int*)(ws + 3 * nb + 1536);             // 256 B (+256 pad)
    int*    order   = (int*)(ws + 3 * nb + 2048);             // n*4
    int2*   bedges  = (int2*)(ws + 4 * nb + 2048);            // 8 MB
    size_t  off1    = 4 * nb + 2048 + (size_t)NBUCKET * BCAP * 8;
    int*    csr     = (int*)(ws + off1);                      // e*4
    __bf16* pw      = (__bf16*)(ws + off1 + (size_t)e * 4);   // 64 KB packed (W1|W2)
    __bf16* z1      = (__bf16*)(ws + off1 + (size_t)e * 4 + 65536);
    __bf16* h1      = z1 + (size_t)n * D;
    __bf16* z2      = h1 + (size_t)n * D;

    int eab = ((e + 3) / 4 + 255) / 256;       // bucketize blocks (625)
    int gb  = (n + 63) / 64;                   // gemm blocks (1563)
    int ab  = ((n * 16) + 255) / 256;          // agg blocks (6250)

    prep_kernel<<<129, 256, 0, stream>>>(W1, W2, pw, bcur, deghist);
    mega1_kernel<<<gb + eab, 256, 0, stream>>>(x, pw, z1, n, gb, src, dst,
                                               bcur, bedges, e, bucketW);
    count2_kernel<<<256, 256, 0, stream>>>(bedges, bcur, counts, dinv, partial, deghist,
                                           n, bucketW, subW);
    scan_top<<<1, 256, 0, stream>>>(partial, deghist, degcur, 256);
    scanfill_kernel<<<256, 256, 0, stream>>>(bedges, bcur, counts, partial, rowptr, csr,
                                             degcur, order, n, bucketW, subW);
    agg1_kernel<<<ab, 256, 0, stream>>>(z1, rowptr, counts, csr, dinv, b1, order, h1, n);
    gemm2_mfma<<<gb, 256, 0, stream>>>(h1, pw + 16384, z2, n);
    agg2_fc_kernel<<<ab, 256, 0, stream>>>(z2, rowptr, counts, csr, dinv, b2, Wfc, bfc,
                                           order, out, n);
}